// Round 1
// baseline (132.280 us; speedup 1.0000x reference)
//
#include <hip/hip_runtime.h>
#include <math.h>

#define BDIM 256
#define WPB (BDIM / 64)

__global__ __launch_bounds__(BDIM) void taskselector_kernel(
    const float* __restrict__ se1,
    const float* __restrict__ se2,
    const float* __restrict__ W,
    const float* __restrict__ bvec,
    const float* __restrict__ u,
    float* __restrict__ out,
    int Brows)
{
    const int lane   = threadIdx.x & 63;
    const int waveid = threadIdx.x >> 6;
    const int wglob  = blockIdx.x * WPB + waveid;
    const int nwaves = gridDim.x * WPB;

    const float4 zero4 = make_float4(0.f, 0.f, 0.f, 0.f);
    const bool extra = (lane < 11);   // 75 float4 per half-row: 64 + 11

    // --- W fragments: constant across rows, held in registers ---
    // W row 0 = elements [0,600), W row 1 = [600,1200). Each row = 150 float4.
    // Column mapping per lane: se1-part float4s {lane, 64+lane}, se2-part {75+lane, 139+lane}.
    const float4* W0 = reinterpret_cast<const float4*>(W);
    const float4* W1 = reinterpret_cast<const float4*>(W + 600);
    float4 w0a = W0[lane];
    float4 w0b = extra ? W0[64 + lane]  : zero4;
    float4 w0c = W0[75 + lane];
    float4 w0d = extra ? W0[139 + lane] : zero4;
    float4 w1a = W1[lane];
    float4 w1b = extra ? W1[64 + lane]  : zero4;
    float4 w1c = W1[75 + lane];
    float4 w1d = extra ? W1[139 + lane] : zero4;
    const float b0 = bvec[0];
    const float b1 = bvec[1];

    for (int row = wglob; row < Brows; row += nwaves) {
        const float4* p1 = reinterpret_cast<const float4*>(se1 + (size_t)row * 300);
        const float4* p2 = reinterpret_cast<const float4*>(se2 + (size_t)row * 300);

        float4 a0 = p1[lane];
        float4 a1 = extra ? p1[64 + lane] : zero4;
        float4 c0 = p2[lane];
        float4 c1 = extra ? p2[64 + lane] : zero4;

        // per-lane partial dots for both tasks
        float d0 = a0.x * w0a.x + a0.y * w0a.y + a0.z * w0a.z + a0.w * w0a.w
                 + a1.x * w0b.x + a1.y * w0b.y + a1.z * w0b.z + a1.w * w0b.w
                 + c0.x * w0c.x + c0.y * w0c.y + c0.z * w0c.z + c0.w * w0c.w
                 + c1.x * w0d.x + c1.y * w0d.y + c1.z * w0d.z + c1.w * w0d.w;
        float d1 = a0.x * w1a.x + a0.y * w1a.y + a0.z * w1a.z + a0.w * w1a.w
                 + a1.x * w1b.x + a1.y * w1b.y + a1.z * w1b.z + a1.w * w1b.w
                 + c0.x * w1c.x + c0.y * w1c.y + c0.z * w1c.z + c0.w * w1c.w
                 + c1.x * w1d.x + c1.y * w1d.y + c1.z * w1d.z + c1.w * w1d.w;

        // 64-lane butterfly reduction (all lanes end with the row totals)
        #pragma unroll
        for (int off = 32; off > 0; off >>= 1) {
            d0 += __shfl_xor(d0, off, 64);
            d1 += __shfl_xor(d1, off, 64);
        }

        // relu(linear)
        float z0 = fmaxf(d0 + b0, 0.f);
        float z1 = fmaxf(d1 + b1, 0.f);

        // log_softmax
        float m   = fmaxf(z0, z1);
        float lse = m + logf(expf(z0 - m) + expf(z1 - m));
        float l0  = z0 - lse;
        float l1  = z1 - lse;

        // gumbel noise
        float u0 = u[(size_t)row * 2 + 0];
        float u1 = u[(size_t)row * 2 + 1];
        float g0 = -logf(-logf(u0 + 1e-20f) + 1e-20f);
        float g1 = -logf(-logf(u1 + 1e-20f) + 1e-20f);

        // softmax(logits + gumbel)
        float q0 = l0 + g0;
        float q1 = l1 + g1;
        float mm = fmaxf(q0, q1);
        float e0 = expf(q0 - mm);
        float e1 = expf(q1 - mm);
        float s  = e0 + e1;
        float y0 = e0 / s;
        float y1 = e1 / s;

        // straight-through: forward value (y_hard - y) + y
        // non-selected: (0 - y) + y == exact 0; selected: (1 - y) + y
        bool  pick0 = (q0 >= q1);          // argmax, first index wins ties
        float s0 = pick0 ? ((1.f - y0) + y0) : 0.f;
        float s1 = pick0 ? 0.f : ((1.f - y1) + y1);

        // scaled store from registers (se read exactly once)
        float4* o = reinterpret_cast<float4*>(out + (size_t)row * 600);
        float4 r;
        r.x = a0.x * s0; r.y = a0.y * s0; r.z = a0.z * s0; r.w = a0.w * s0;
        o[lane] = r;
        if (extra) {
            r.x = a1.x * s0; r.y = a1.y * s0; r.z = a1.z * s0; r.w = a1.w * s0;
            o[64 + lane] = r;
        }
        r.x = c0.x * s1; r.y = c0.y * s1; r.z = c0.z * s1; r.w = c0.w * s1;
        o[75 + lane] = r;
        if (extra) {
            r.x = c1.x * s1; r.y = c1.y * s1; r.z = c1.z * s1; r.w = c1.w * s1;
            o[139 + lane] = r;
        }
    }
}

extern "C" void kernel_launch(void* const* d_in, const int* in_sizes, int n_in,
                              void* d_out, int out_size, void* d_ws, size_t ws_size,
                              hipStream_t stream) {
    const float* se1 = (const float*)d_in[0];
    const float* se2 = (const float*)d_in[1];
    const float* W   = (const float*)d_in[2];
    const float* b   = (const float*)d_in[3];
    const float* u   = (const float*)d_in[4];
    float* out = (float*)d_out;

    const int Brows = in_sizes[0] / 300;   // 131072

    // memory-bound: cap grid, grid-stride the rows (16 rows/wave at 2048 blocks)
    int blocks = 2048;
    int maxBlocks = (Brows + WPB - 1) / WPB;
    if (blocks > maxBlocks) blocks = maxBlocks;

    taskselector_kernel<<<blocks, BDIM, 0, stream>>>(se1, se2, W, b, u, out, Brows);
}

// Round 2
// 131.092 us; speedup vs baseline: 1.0091x; 1.0091x over previous
//
#include <hip/hip_runtime.h>
#include <math.h>

typedef float f4 __attribute__((ext_vector_type(4)));

#define BDIM 256
#define WPB (BDIM / 64)

__device__ __forceinline__ float dot4(f4 a, f4 w) {
    return a[0]*w[0] + a[1]*w[1] + a[2]*w[2] + a[3]*w[3];
}

__global__ __launch_bounds__(BDIM) void taskselector_kernel(
    const float* __restrict__ se1,
    const float* __restrict__ se2,
    const float* __restrict__ W,
    const float* __restrict__ bvec,
    const float* __restrict__ u,
    float* __restrict__ out,
    int Brows)
{
    const int lane   = threadIdx.x & 63;
    const int waveid = threadIdx.x >> 6;
    const int wglob  = blockIdx.x * WPB + waveid;
    const int nwaves = gridDim.x * WPB;

    const bool extra = (lane < 11);     // 75 float4 per half-row: 64 + 11
    const f4 zero = (f4)0.f;

    // W held in registers, reused across all rows
    const f4* W0 = (const f4*)(W);
    const f4* W1 = (const f4*)(W + 600);
    f4 w0a = W0[lane];
    f4 w0b = extra ? W0[64 + lane]  : zero;
    f4 w0c = W0[75 + lane];
    f4 w0d = extra ? W0[139 + lane] : zero;
    f4 w1a = W1[lane];
    f4 w1b = extra ? W1[64 + lane]  : zero;
    f4 w1c = W1[75 + lane];
    f4 w1d = extra ? W1[139 + lane] : zero;
    const float b0 = bvec[0];
    const float b1 = bvec[1];

    // 2 rows per wave-iteration: two independent load->reduce->store chains
    for (int base = wglob * 2; base < Brows; base += nwaves * 2) {
        const int rowA = base;
        const int rowB = base + 1;   // Brows even, always valid

        const f4* pA1 = (const f4*)(se1 + (size_t)rowA * 300);
        const f4* pA2 = (const f4*)(se2 + (size_t)rowA * 300);
        const f4* pB1 = (const f4*)(se1 + (size_t)rowB * 300);
        const f4* pB2 = (const f4*)(se2 + (size_t)rowB * 300);

        // streaming loads (no L2 allocate) — read once, never reused
        f4 aA0 = __builtin_nontemporal_load(pA1 + lane);
        f4 cA0 = __builtin_nontemporal_load(pA2 + lane);
        f4 aB0 = __builtin_nontemporal_load(pB1 + lane);
        f4 cB0 = __builtin_nontemporal_load(pB2 + lane);
        f4 aA1 = zero, cA1 = zero, aB1 = zero, cB1 = zero;
        if (extra) {
            aA1 = __builtin_nontemporal_load(pA1 + 64 + lane);
            cA1 = __builtin_nontemporal_load(pA2 + 64 + lane);
            aB1 = __builtin_nontemporal_load(pB1 + 64 + lane);
            cB1 = __builtin_nontemporal_load(pB2 + 64 + lane);
        }

        // per-lane partial dots, both tasks, both rows
        float dA0 = dot4(aA0, w0a) + dot4(aA1, w0b) + dot4(cA0, w0c) + dot4(cA1, w0d);
        float dA1 = dot4(aA0, w1a) + dot4(aA1, w1b) + dot4(cA0, w1c) + dot4(cA1, w1d);
        float dB0 = dot4(aB0, w0a) + dot4(aB1, w0b) + dot4(cB0, w0c) + dot4(cB1, w0d);
        float dB1 = dot4(aB0, w1a) + dot4(aB1, w1b) + dot4(cB0, w1c) + dot4(cB1, w1d);

        // interleaved 64-lane butterflies (4 independent chains share latency)
        #pragma unroll
        for (int off = 32; off > 0; off >>= 1) {
            dA0 += __shfl_xor(dA0, off, 64);
            dA1 += __shfl_xor(dA1, off, 64);
            dB0 += __shfl_xor(dB0, off, 64);
            dB1 += __shfl_xor(dB1, off, 64);
        }

        // ---------- epilogue row A ----------
        float zA0 = fmaxf(dA0 + b0, 0.f);
        float zA1 = fmaxf(dA1 + b1, 0.f);
        float mA  = fmaxf(zA0, zA1);
        float lseA = mA + logf(expf(zA0 - mA) + expf(zA1 - mA));
        float u0A = u[(size_t)rowA * 2 + 0];
        float u1A = u[(size_t)rowA * 2 + 1];
        float qA0 = (zA0 - lseA) + (-logf(-logf(u0A + 1e-20f) + 1e-20f));
        float qA1 = (zA1 - lseA) + (-logf(-logf(u1A + 1e-20f) + 1e-20f));
        float mmA = fmaxf(qA0, qA1);
        float eA0 = expf(qA0 - mmA);
        float eA1 = expf(qA1 - mmA);
        float sA  = eA0 + eA1;
        float yA0 = eA0 / sA;
        float yA1 = eA1 / sA;
        bool  pickA0 = (qA0 >= qA1);
        float sA0 = pickA0 ? ((1.f - yA0) + yA0) : 0.f;
        float sA1 = pickA0 ? 0.f : ((1.f - yA1) + yA1);

        // ---------- epilogue row B ----------
        float zB0 = fmaxf(dB0 + b0, 0.f);
        float zB1 = fmaxf(dB1 + b1, 0.f);
        float mB  = fmaxf(zB0, zB1);
        float lseB = mB + logf(expf(zB0 - mB) + expf(zB1 - mB));
        float u0B = u[(size_t)rowB * 2 + 0];
        float u1B = u[(size_t)rowB * 2 + 1];
        float qB0 = (zB0 - lseB) + (-logf(-logf(u0B + 1e-20f) + 1e-20f));
        float qB1 = (zB1 - lseB) + (-logf(-logf(u1B + 1e-20f) + 1e-20f));
        float mmB = fmaxf(qB0, qB1);
        float eB0 = expf(qB0 - mmB);
        float eB1 = expf(qB1 - mmB);
        float sB  = eB0 + eB1;
        float yB0 = eB0 / sB;
        float yB1 = eB1 / sB;
        bool  pickB0 = (qB0 >= qB1);
        float sB0 = pickB0 ? ((1.f - yB0) + yB0) : 0.f;
        float sB1 = pickB0 ? 0.f : ((1.f - yB1) + yB1);

        // ---------- streaming stores ----------
        f4* oA = (f4*)(out + (size_t)rowA * 600);
        f4* oB = (f4*)(out + (size_t)rowB * 600);
        __builtin_nontemporal_store(aA0 * sA0, oA + lane);
        __builtin_nontemporal_store(cA0 * sA1, oA + 75 + lane);
        __builtin_nontemporal_store(aB0 * sB0, oB + lane);
        __builtin_nontemporal_store(cB0 * sB1, oB + 75 + lane);
        if (extra) {
            __builtin_nontemporal_store(aA1 * sA0, oA + 64 + lane);
            __builtin_nontemporal_store(cA1 * sA1, oA + 139 + lane);
            __builtin_nontemporal_store(aB1 * sB0, oB + 64 + lane);
            __builtin_nontemporal_store(cB1 * sB1, oB + 139 + lane);
        }
    }
}

extern "C" void kernel_launch(void* const* d_in, const int* in_sizes, int n_in,
                              void* d_out, int out_size, void* d_ws, size_t ws_size,
                              hipStream_t stream) {
    const float* se1 = (const float*)d_in[0];
    const float* se2 = (const float*)d_in[1];
    const float* W   = (const float*)d_in[2];
    const float* b   = (const float*)d_in[3];
    const float* u   = (const float*)d_in[4];
    float* out = (float*)d_out;

    const int Brows = in_sizes[0] / 300;   // 131072

    int blocks = 2048;
    int maxBlocks = (Brows + WPB * 2 - 1) / (WPB * 2);
    if (blocks > maxBlocks) blocks = maxBlocks;

    taskselector_kernel<<<blocks, BDIM, 0, stream>>>(se1, se2, W, b, u, out, Brows);
}